// Round 1
// baseline (743.222 us; speedup 1.0000x reference)
//
#include <hip/hip_runtime.h>

#define D 128
#define TM 16

// ---------------- degree count ----------------
__global__ void deg_kernel(const int* __restrict__ rows, int* __restrict__ deg, int E) {
    int e = blockIdx.x * blockDim.x + threadIdx.x;
    if (e < E) atomicAdd(&deg[rows[e]], 1);
}

// ---------------- single-block exclusive scan over N=100000 ----------------
__global__ void scan_kernel(const int* __restrict__ deg, int* __restrict__ row_start, int n) {
    __shared__ int sums[1024];
    int t = threadIdx.x;
    int chunk = (n + 1023) / 1024;
    int lo = t * chunk;
    int hi = lo + chunk; if (hi > n) hi = n;
    int s = 0;
    for (int i = lo; i < hi; ++i) s += deg[i];
    sums[t] = s;
    __syncthreads();
    // Hillis-Steele inclusive scan over the 1024 partials
    for (int off = 1; off < 1024; off <<= 1) {
        int v = 0;
        if (t >= off) v = sums[t - off];
        __syncthreads();
        sums[t] += v;
        __syncthreads();
    }
    int run = (t == 0) ? 0 : sums[t - 1];
    for (int i = lo; i < hi; ++i) { row_start[i] = run; run += deg[i]; }
    if (t == 1023) row_start[n] = sums[1023];
}

// ---------------- fill CSR buckets ----------------
__global__ void bucket_kernel(const int* __restrict__ ei, const int* __restrict__ row_start,
                              int* __restrict__ cursor, int* __restrict__ col_sorted, int E) {
    int e = blockIdx.x * blockDim.x + threadIdx.x;
    if (e >= E) return;
    int r = ei[e];
    int c = ei[E + e];
    int slot = atomicAdd(&cursor[r], 1);
    col_sorted[row_start[r] + slot] = c;
}

// ---------------- weight prep: Wt[k][j] = W_l[j][k] (k<128), W_r[j][k-128]; bias = b_l+b_r ----------------
__global__ void prepw_kernel(const float* __restrict__ Wl, const float* __restrict__ bl,
                             const float* __restrict__ Wr, const float* __restrict__ br,
                             float* __restrict__ Wt, float* __restrict__ bias) {
    int t = blockIdx.x * blockDim.x + threadIdx.x;
    if (t < D * D) {
        int j = t & (D - 1);
        int k = t >> 7;
        Wt[t]         = Wl[j * D + k];
        Wt[D * D + t] = Wr[j * D + k];
    }
    if (t < D) bias[t] = bl[t] + br[t];
}

// ---------------- gather: one wave per node, mean of neighbor rows ----------------
__global__ void gather_kernel(const float* __restrict__ x, const int* __restrict__ col_sorted,
                              const int* __restrict__ row_start, float* __restrict__ mean, int n) {
    int wave = (int)((blockIdx.x * (size_t)blockDim.x + threadIdx.x) >> 6);
    int lane = threadIdx.x & 63;
    if (wave >= n) return;
    int s = row_start[wave];
    int e = row_start[wave + 1];
    float a0 = 0.f, a1 = 0.f;
    int j = s;
    for (; j + 1 < e; j += 2) {
        int c0 = col_sorted[j];
        int c1 = col_sorted[j + 1];
        float2 v0 = *(const float2*)(x + (size_t)c0 * D + lane * 2);
        float2 v1 = *(const float2*)(x + (size_t)c1 * D + lane * 2);
        a0 += v0.x + v1.x;
        a1 += v0.y + v1.y;
    }
    if (j < e) {
        int c = col_sorted[j];
        float2 v = *(const float2*)(x + (size_t)c * D + lane * 2);
        a0 += v.x;
        a1 += v.y;
    }
    float inv = (e > s) ? 1.0f / (float)(e - s) : 0.0f;
    float2 o;
    o.x = a0 * inv;
    o.y = a1 * inv;
    *(float2*)(mean + (size_t)wave * D + lane * 2) = o;
}

// ---------------- GEMM: out[i][j] = sum_k mean[i][k]*Wt[k][j] + sum_k x[i][k]*Wt[128+k][j] + bias[j]
// thread = column j (128 threads), block = TM nodes. A-reads are block-uniform -> s_load;
// W-read is one coalesced vector load per k. VALU-bound by design.
__global__ __launch_bounds__(128) void gemm_kernel(const float* __restrict__ mean,
                                                   const float* __restrict__ x,
                                                   const float* __restrict__ Wt,
                                                   const float* __restrict__ bias,
                                                   float* __restrict__ out, int n) {
    int j = threadIdx.x;
    int n0 = blockIdx.x * TM;
    float acc[TM];
    float b = bias[j];
#pragma unroll
    for (int i = 0; i < TM; ++i) acc[i] = b;

    const float* A0 = mean + (size_t)n0 * D;
    const float* A1 = x + (size_t)n0 * D;

#pragma unroll 4
    for (int k = 0; k < D; ++k) {
        float w = Wt[k * D + j];
#pragma unroll
        for (int i = 0; i < TM; ++i)
            acc[i] = fmaf(A0[(size_t)i * D + k], w, acc[i]);
    }
#pragma unroll 4
    for (int k = 0; k < D; ++k) {
        float w = Wt[(D + k) * D + j];
#pragma unroll
        for (int i = 0; i < TM; ++i)
            acc[i] = fmaf(A1[(size_t)i * D + k], w, acc[i]);
    }

#pragma unroll
    for (int i = 0; i < TM; ++i)
        if (n0 + i < n) out[(size_t)(n0 + i) * D + j] = acc[i];
}

extern "C" void kernel_launch(void* const* d_in, const int* in_sizes, int n_in,
                              void* d_out, int out_size, void* d_ws, size_t ws_size,
                              hipStream_t stream) {
    const float* x  = (const float*)d_in[0];
    const int*   ei = (const int*)d_in[1];
    const float* Wl = (const float*)d_in[2];
    const float* bl = (const float*)d_in[3];
    const float* Wr = (const float*)d_in[4];
    const float* br = (const float*)d_in[5];
    float* out = (float*)d_out;

    const int n = in_sizes[0] / D;       // 100000
    const int E = in_sizes[1] / 2;       // 1600000

    // workspace bump allocator (1 KiB aligned)
    char* p = (char*)d_ws;
    auto alloc = [&](size_t bytes) {
        char* r = p;
        p += (bytes + 1023) & ~(size_t)1023;
        return r;
    };
    int*   deg        = (int*)alloc((size_t)n * 4);
    int*   cursor     = (int*)alloc((size_t)n * 4);
    int*   row_start  = (int*)alloc((size_t)(n + 1) * 4);
    int*   col_sorted = (int*)alloc((size_t)E * 4);
    float* Wt         = (float*)alloc((size_t)2 * D * D * 4);
    float* bias       = (float*)alloc((size_t)D * 4);
    float* mean       = (float*)alloc((size_t)n * D * 4);

    hipMemsetAsync(deg, 0, (size_t)n * 4, stream);
    hipMemsetAsync(cursor, 0, (size_t)n * 4, stream);

    deg_kernel<<<(E + 255) / 256, 256, 0, stream>>>(ei, deg, E);
    scan_kernel<<<1, 1024, 0, stream>>>(deg, row_start, n);
    bucket_kernel<<<(E + 255) / 256, 256, 0, stream>>>(ei, row_start, cursor, col_sorted, E);
    prepw_kernel<<<(D * D + 255) / 256, 256, 0, stream>>>(Wl, bl, Wr, br, Wt, bias);
    gather_kernel<<<(n + 3) / 4, 256, 0, stream>>>(x, col_sorted, row_start, mean, n);
    gemm_kernel<<<(n + TM - 1) / TM, 128, 0, stream>>>(mean, x, Wt, bias, out, n);
}

// Round 2
// 673.431 us; speedup vs baseline: 1.1036x; 1.1036x over previous
//
#include <hip/hip_runtime.h>

#define D 128

typedef __attribute__((ext_vector_type(8))) short short8;
typedef __attribute__((ext_vector_type(4))) float f32x4;

__device__ __forceinline__ unsigned short f2bf(float f) {
    unsigned u = __float_as_uint(f);
    return (unsigned short)((u + 0x7fffu + ((u >> 16) & 1u)) >> 16);
}

// ---------------- split x into bf16 hi + bf16 lo(residual) ----------------
__global__ void split_kernel(const float4* __restrict__ x, uint2* __restrict__ xh,
                             uint2* __restrict__ xl, int n4) {
    int i = blockIdx.x * blockDim.x + threadIdx.x;
    if (i >= n4) return;
    float4 v = x[i];
    unsigned short h0 = f2bf(v.x), h1 = f2bf(v.y), h2 = f2bf(v.z), h3 = f2bf(v.w);
    float r0 = v.x - __uint_as_float((unsigned)h0 << 16);
    float r1 = v.y - __uint_as_float((unsigned)h1 << 16);
    float r2 = v.z - __uint_as_float((unsigned)h2 << 16);
    float r3 = v.w - __uint_as_float((unsigned)h3 << 16);
    unsigned short l0 = f2bf(r0), l1 = f2bf(r1), l2 = f2bf(r2), l3 = f2bf(r3);
    uint2 hh, ll;
    hh.x = (unsigned)h0 | ((unsigned)h1 << 16);
    hh.y = (unsigned)h2 | ((unsigned)h3 << 16);
    ll.x = (unsigned)l0 | ((unsigned)l1 << 16);
    ll.y = (unsigned)l2 | ((unsigned)l3 << 16);
    xh[i] = hh;
    xl[i] = ll;
}

// ---------------- weight prep: rows 0..127 = W_l, 128..255 = W_r, split hi/lo; bias = b_l+b_r ----------------
__global__ void prepw_kernel(const float* __restrict__ Wl_in, const float* __restrict__ bl,
                             const float* __restrict__ Wr_in, const float* __restrict__ br,
                             unsigned short* __restrict__ wh, unsigned short* __restrict__ wl,
                             float* __restrict__ bias) {
    int t = blockIdx.x * blockDim.x + threadIdx.x;
    if (t < 2 * D * D) {
        int n = t >> 7;
        int k = t & (D - 1);
        float v = (n < D) ? Wl_in[n * D + k] : Wr_in[(n - D) * D + k];
        unsigned short h = f2bf(v);
        float r = v - __uint_as_float((unsigned)h << 16);
        wh[t] = h;
        wl[t] = f2bf(r);
    }
    if (t < D) bias[t] = bl[t] + br[t];
}

// ---------------- degree count ----------------
__global__ void deg_kernel(const int* __restrict__ rows, int* __restrict__ deg, int E) {
    int e = blockIdx.x * blockDim.x + threadIdx.x;
    if (e < E) atomicAdd(&deg[rows[e]], 1);
}

// ---------------- single-block scan; also writes cursor = row_start ----------------
__global__ void scan_kernel(const int* __restrict__ deg, int* __restrict__ row_start,
                            int* __restrict__ cursor, int n) {
    __shared__ int sums[1024];
    int t = threadIdx.x;
    int chunk = (n + 1023) / 1024;
    int lo = t * chunk;
    int hi = lo + chunk; if (hi > n) hi = n;
    int s = 0;
    for (int i = lo; i < hi; ++i) s += deg[i];
    sums[t] = s;
    __syncthreads();
    for (int off = 1; off < 1024; off <<= 1) {
        int v = 0;
        if (t >= off) v = sums[t - off];
        __syncthreads();
        sums[t] += v;
        __syncthreads();
    }
    int run = (t == 0) ? 0 : sums[t - 1];
    for (int i = lo; i < hi; ++i) {
        row_start[i] = run;
        cursor[i] = run;
        run += deg[i];
    }
    if (t == 1023) row_start[n] = sums[1023];
}

// ---------------- fill CSR buckets (cursor holds absolute positions) ----------------
__global__ void bucket_kernel(const int* __restrict__ ei, int* __restrict__ cursor,
                              int* __restrict__ col_sorted, int E) {
    int e = blockIdx.x * blockDim.x + threadIdx.x;
    if (e >= E) return;
    int r = ei[e];
    int c = ei[E + e];
    int pos = atomicAdd(&cursor[r], 1);
    col_sorted[pos] = c;
}

// ---------------- bf16x3 MFMA GEMM: [y_l | out] = x @ [W_l ; W_r]^T (+bias on out half)
// block = 64 rows, 4 waves; wave w covers cols 64w..64w+63 (w<2 -> y_l bf16, w>=2 -> out fp32)
__global__ __launch_bounds__(256) void mm_kernel(const unsigned short* __restrict__ xh,
                                                 const unsigned short* __restrict__ xl,
                                                 const unsigned short* __restrict__ wh,
                                                 const unsigned short* __restrict__ wl,
                                                 const float* __restrict__ bias,
                                                 unsigned short* __restrict__ yl,
                                                 float* __restrict__ out, int n) {
    int w = threadIdx.x >> 6;
    int l = threadIdx.x & 63;
    int ml = l & 15;   // A row / B col within fragment
    int kq = l >> 4;   // k-quad
    int m0 = blockIdx.x * 64;
    int n0 = w * 64;

    f32x4 acc[4][4];
#pragma unroll
    for (int a = 0; a < 4; ++a)
#pragma unroll
        for (int b = 0; b < 4; ++b) acc[a][b] = (f32x4){0.f, 0.f, 0.f, 0.f};

#pragma unroll
    for (int ks = 0; ks < 4; ++ks) {
        short8 Ah[4], Al[4];
#pragma unroll
        for (int mf = 0; mf < 4; ++mf) {
            int row = m0 + mf * 16 + ml;
            if (row > n - 1) row = n - 1;              // clamp tail loads
            size_t off = (size_t)row * D + ks * 32 + kq * 8;
            Ah[mf] = *(const short8*)(xh + off);
            Al[mf] = *(const short8*)(xl + off);
        }
#pragma unroll
        for (int nf = 0; nf < 4; ++nf) {
            size_t boff = (size_t)(n0 + nf * 16 + ml) * D + ks * 32 + kq * 8;
            short8 Bh = *(const short8*)(wh + boff);
            short8 Bl = *(const short8*)(wl + boff);
#pragma unroll
            for (int mf = 0; mf < 4; ++mf) {
                acc[mf][nf] = __builtin_amdgcn_mfma_f32_16x16x32_bf16(Ah[mf], Bh, acc[mf][nf], 0, 0, 0);
                acc[mf][nf] = __builtin_amdgcn_mfma_f32_16x16x32_bf16(Ah[mf], Bl, acc[mf][nf], 0, 0, 0);
                acc[mf][nf] = __builtin_amdgcn_mfma_f32_16x16x32_bf16(Al[mf], Bh, acc[mf][nf], 0, 0, 0);
            }
        }
    }

    if (n0 < D) {
        // y_l half: store bf16
#pragma unroll
        for (int nf = 0; nf < 4; ++nf) {
            int col = n0 + nf * 16 + ml;
#pragma unroll
            for (int mf = 0; mf < 4; ++mf) {
                int rbase = m0 + mf * 16 + kq * 4;
#pragma unroll
                for (int r = 0; r < 4; ++r) {
                    int row = rbase + r;
                    if (row < n) yl[(size_t)row * D + col] = f2bf(acc[mf][nf][r]);
                }
            }
        }
    } else {
        // out half: fp32 + bias
#pragma unroll
        for (int nf = 0; nf < 4; ++nf) {
            int col = n0 - D + nf * 16 + ml;
            float bv = bias[col];
#pragma unroll
            for (int mf = 0; mf < 4; ++mf) {
                int rbase = m0 + mf * 16 + kq * 4;
#pragma unroll
                for (int r = 0; r < 4; ++r) {
                    int row = rbase + r;
                    if (row < n) out[(size_t)row * D + col] = acc[mf][nf][r] + bv;
                }
            }
        }
    }
}

// ---------------- gather: one wave per node; out[i] += mean of bf16 y_l rows ----------------
__global__ void gather_kernel(const unsigned short* __restrict__ yl,
                              const int* __restrict__ col_sorted,
                              const int* __restrict__ row_start,
                              float* __restrict__ out, int n) {
    int wave = (int)((blockIdx.x * (size_t)blockDim.x + threadIdx.x) >> 6);
    int lane = threadIdx.x & 63;
    if (wave >= n) return;
    int s = row_start[wave];
    int e = row_start[wave + 1];
    float a0 = 0.f, a1 = 0.f;
    int j = s;
    for (; j + 3 < e; j += 4) {
        int c0 = col_sorted[j], c1 = col_sorted[j + 1], c2 = col_sorted[j + 2], c3 = col_sorted[j + 3];
        unsigned v0 = *(const unsigned*)(yl + (size_t)c0 * D + 2 * lane);
        unsigned v1 = *(const unsigned*)(yl + (size_t)c1 * D + 2 * lane);
        unsigned v2 = *(const unsigned*)(yl + (size_t)c2 * D + 2 * lane);
        unsigned v3 = *(const unsigned*)(yl + (size_t)c3 * D + 2 * lane);
        a0 += __uint_as_float(v0 << 16) + __uint_as_float(v1 << 16) +
              __uint_as_float(v2 << 16) + __uint_as_float(v3 << 16);
        a1 += __uint_as_float(v0 & 0xffff0000u) + __uint_as_float(v1 & 0xffff0000u) +
              __uint_as_float(v2 & 0xffff0000u) + __uint_as_float(v3 & 0xffff0000u);
    }
    for (; j < e; ++j) {
        unsigned v = *(const unsigned*)(yl + (size_t)col_sorted[j] * D + 2 * lane);
        a0 += __uint_as_float(v << 16);
        a1 += __uint_as_float(v & 0xffff0000u);
    }
    float inv = (e > s) ? 1.0f / (float)(e - s) : 0.0f;
    float2* po = (float2*)(out + (size_t)wave * D + 2 * lane);
    float2 cur = *po;
    cur.x += a0 * inv;
    cur.y += a1 * inv;
    *po = cur;
}

extern "C" void kernel_launch(void* const* d_in, const int* in_sizes, int n_in,
                              void* d_out, int out_size, void* d_ws, size_t ws_size,
                              hipStream_t stream) {
    const float* x  = (const float*)d_in[0];
    const int*   ei = (const int*)d_in[1];
    const float* Wl = (const float*)d_in[2];
    const float* bl = (const float*)d_in[3];
    const float* Wr = (const float*)d_in[4];
    const float* br = (const float*)d_in[5];
    float* out = (float*)d_out;

    const int n = in_sizes[0] / D;       // 100000
    const int E = in_sizes[1] / 2;       // 1600000

    char* p = (char*)d_ws;
    auto alloc = [&](size_t bytes) {
        char* r = p;
        p += (bytes + 1023) & ~(size_t)1023;
        return r;
    };
    int*   deg        = (int*)alloc((size_t)n * 4);
    int*   cursor     = (int*)alloc((size_t)n * 4);
    int*   row_start  = (int*)alloc((size_t)(n + 1) * 4);
    int*   col_sorted = (int*)alloc((size_t)E * 4);
    unsigned short* wh   = (unsigned short*)alloc((size_t)2 * D * D * 2);
    unsigned short* wlsp = (unsigned short*)alloc((size_t)2 * D * D * 2);
    float* bias       = (float*)alloc((size_t)D * 4);
    unsigned short* xh = (unsigned short*)alloc((size_t)n * D * 2);
    unsigned short* xl = (unsigned short*)alloc((size_t)n * D * 2);
    unsigned short* yl = (unsigned short*)alloc((size_t)n * D * 2);

    hipMemsetAsync(deg, 0, (size_t)n * 4, stream);

    int n4 = n * D / 4;
    split_kernel<<<(n4 + 255) / 256, 256, 0, stream>>>((const float4*)x, (uint2*)xh, (uint2*)xl, n4);
    prepw_kernel<<<(2 * D * D + 255) / 256, 256, 0, stream>>>(Wl, bl, Wr, br, wh, wlsp, bias);
    deg_kernel<<<(E + 255) / 256, 256, 0, stream>>>(ei, deg, E);
    scan_kernel<<<1, 1024, 0, stream>>>(deg, row_start, cursor, n);
    bucket_kernel<<<(E + 255) / 256, 256, 0, stream>>>(ei, cursor, col_sorted, E);
    mm_kernel<<<(n + 63) / 64, 256, 0, stream>>>(xh, xl, wh, wlsp, bias, yl, out, n);
    gather_kernel<<<(n * 64 + 255) / 256, 256, 0, stream>>>(yl, col_sorted, row_start, out, n);
}

// Round 3
// 477.372 us; speedup vs baseline: 1.5569x; 1.4107x over previous
//
#include <hip/hip_runtime.h>

#define D 128

typedef __attribute__((ext_vector_type(8))) short short8;
typedef __attribute__((ext_vector_type(4))) float f32x4;

__device__ __forceinline__ unsigned short f2bf(float f) {
    unsigned u = __float_as_uint(f);
    return (unsigned short)((u + 0x7fffu + ((u >> 16) & 1u)) >> 16);
}

// ---------------- split x into bf16 hi + bf16 lo(residual) ----------------
__global__ void split_kernel(const float4* __restrict__ x, uint2* __restrict__ xh,
                             uint2* __restrict__ xl, int n4) {
    int i = blockIdx.x * blockDim.x + threadIdx.x;
    if (i >= n4) return;
    float4 v = x[i];
    unsigned short h0 = f2bf(v.x), h1 = f2bf(v.y), h2 = f2bf(v.z), h3 = f2bf(v.w);
    float r0 = v.x - __uint_as_float((unsigned)h0 << 16);
    float r1 = v.y - __uint_as_float((unsigned)h1 << 16);
    float r2 = v.z - __uint_as_float((unsigned)h2 << 16);
    float r3 = v.w - __uint_as_float((unsigned)h3 << 16);
    unsigned short l0 = f2bf(r0), l1 = f2bf(r1), l2 = f2bf(r2), l3 = f2bf(r3);
    uint2 hh, ll;
    hh.x = (unsigned)h0 | ((unsigned)h1 << 16);
    hh.y = (unsigned)h2 | ((unsigned)h3 << 16);
    ll.x = (unsigned)l0 | ((unsigned)l1 << 16);
    ll.y = (unsigned)l2 | ((unsigned)l3 << 16);
    xh[i] = hh;
    xl[i] = ll;
}

// ---------------- weight prep ----------------
__global__ void prepw_kernel(const float* __restrict__ Wl_in, const float* __restrict__ bl,
                             const float* __restrict__ Wr_in, const float* __restrict__ br,
                             unsigned short* __restrict__ wh, unsigned short* __restrict__ wl,
                             float* __restrict__ bias) {
    int t = blockIdx.x * blockDim.x + threadIdx.x;
    if (t < 2 * D * D) {
        int n = t >> 7;
        int k = t & (D - 1);
        float v = (n < D) ? Wl_in[n * D + k] : Wr_in[(n - D) * D + k];
        unsigned short h = f2bf(v);
        float r = v - __uint_as_float((unsigned)h << 16);
        wh[t] = h;
        wl[t] = f2bf(r);
    }
    if (t < D) bias[t] = bl[t] + br[t];
}

// ---------------- degree count ----------------
__global__ void deg_kernel(const int* __restrict__ rows, int* __restrict__ deg, int E) {
    int e = blockIdx.x * blockDim.x + threadIdx.x;
    if (e < E) atomicAdd(&deg[rows[e]], 1);
}

// ---------------- multi-block scan, pass 1: per-chunk (1024 elem) sums ----------------
__global__ __launch_bounds__(256) void partial_kernel(const int* __restrict__ deg,
                                                      int* __restrict__ partial, int n) {
    int b = blockIdx.x, t = threadIdx.x;
    int base = b * 1024 + t * 4;
    int s = 0;
    if (base + 3 < n) {
        int4 v = *(const int4*)(deg + base);
        s = v.x + v.y + v.z + v.w;
    } else {
        for (int i = 0; i < 4; ++i) if (base + i < n) s += deg[base + i];
    }
    for (int off = 32; off; off >>= 1) s += __shfl_down(s, off, 64);
    __shared__ int wsum[4];
    int lane = t & 63, w = t >> 6;
    if (lane == 0) wsum[w] = s;
    __syncthreads();
    if (t == 0) partial[b] = wsum[0] + wsum[1] + wsum[2] + wsum[3];
}

// ---------------- pass 2: exclusive-scan the partials (tiny) ----------------
__global__ void scanp_kernel(int* __restrict__ partial, int* __restrict__ row_start,
                             int nb, int n) {
    __shared__ int s[128];
    int t = threadIdx.x;
    int v = (t < nb) ? partial[t] : 0;
    s[t] = v;
    __syncthreads();
    for (int off = 1; off < 128; off <<= 1) {
        int u = (t >= off) ? s[t - off] : 0;
        __syncthreads();
        s[t] += u;
        __syncthreads();
    }
    if (t < nb) partial[t] = s[t] - v;   // exclusive
    if (t == 127) row_start[n] = s[127]; // total
}

// ---------------- pass 3: per-chunk exclusive scan + offset; writes row_start & cursor ----------------
__global__ __launch_bounds__(256) void scanf_kernel(const int* __restrict__ deg,
                                                    const int* __restrict__ partial,
                                                    int* __restrict__ row_start,
                                                    int* __restrict__ cursor, int n) {
    int b = blockIdx.x, t = threadIdx.x;
    int base = b * 1024 + t * 4;
    int d0 = 0, d1 = 0, d2 = 0, d3 = 0;
    if (base + 3 < n) {
        int4 v = *(const int4*)(deg + base);
        d0 = v.x; d1 = v.y; d2 = v.z; d3 = v.w;
    } else {
        if (base < n)     d0 = deg[base];
        if (base + 1 < n) d1 = deg[base + 1];
        if (base + 2 < n) d2 = deg[base + 2];
        if (base + 3 < n) d3 = deg[base + 3];
    }
    int tsum = d0 + d1 + d2 + d3;
    // wave inclusive scan of tsum
    int lane = t & 63, w = t >> 6;
    int s = tsum;
    for (int off = 1; off < 64; off <<= 1) {
        int u = __shfl_up(s, off, 64);
        if (lane >= off) s += u;
    }
    __shared__ int wsum[4];
    if (lane == 63) wsum[w] = s;
    __syncthreads();
    __shared__ int woff[4];
    if (t == 0) {
        int run = 0;
        for (int i = 0; i < 4; ++i) { woff[i] = run; run += wsum[i]; }
    }
    __syncthreads();
    int ex = s - tsum + woff[w];          // block-exclusive prefix of tsum
    int off0 = partial[b] + ex;
    int p0 = off0, p1 = p0 + d0, p2 = p1 + d1, p3 = p2 + d2;
    if (base + 3 < n) {
        *(int4*)(row_start + base) = make_int4(p0, p1, p2, p3);
        *(int4*)(cursor + base)    = make_int4(p0, p1, p2, p3);
    } else {
        if (base < n)     { row_start[base] = p0;     cursor[base] = p0; }
        if (base + 1 < n) { row_start[base + 1] = p1; cursor[base + 1] = p1; }
        if (base + 2 < n) { row_start[base + 2] = p2; cursor[base + 2] = p2; }
        if (base + 3 < n) { row_start[base + 3] = p3; cursor[base + 3] = p3; }
    }
}

// ---------------- fill CSR buckets (cursor holds absolute positions) ----------------
__global__ void bucket_kernel(const int* __restrict__ ei, int* __restrict__ cursor,
                              int* __restrict__ col_sorted, int E) {
    int e = blockIdx.x * blockDim.x + threadIdx.x;
    if (e >= E) return;
    int r = ei[e];
    int c = ei[E + e];
    int pos = atomicAdd(&cursor[r], 1);
    col_sorted[pos] = c;
}

// ---------------- bf16x3 MFMA GEMM: [y_l | out] = x @ [W_l ; W_r]^T (+bias on out half) ----------------
__global__ __launch_bounds__(256) void mm_kernel(const unsigned short* __restrict__ xh,
                                                 const unsigned short* __restrict__ xl,
                                                 const unsigned short* __restrict__ wh,
                                                 const unsigned short* __restrict__ wl,
                                                 const float* __restrict__ bias,
                                                 unsigned short* __restrict__ yl,
                                                 float* __restrict__ out, int n) {
    int w = threadIdx.x >> 6;
    int l = threadIdx.x & 63;
    int ml = l & 15;
    int kq = l >> 4;
    int m0 = blockIdx.x * 64;
    int n0 = w * 64;

    f32x4 acc[4][4];
#pragma unroll
    for (int a = 0; a < 4; ++a)
#pragma unroll
        for (int b = 0; b < 4; ++b) acc[a][b] = (f32x4){0.f, 0.f, 0.f, 0.f};

#pragma unroll
    for (int ks = 0; ks < 4; ++ks) {
        short8 Ah[4], Al[4];
#pragma unroll
        for (int mf = 0; mf < 4; ++mf) {
            int row = m0 + mf * 16 + ml;
            if (row > n - 1) row = n - 1;
            size_t off = (size_t)row * D + ks * 32 + kq * 8;
            Ah[mf] = *(const short8*)(xh + off);
            Al[mf] = *(const short8*)(xl + off);
        }
#pragma unroll
        for (int nf = 0; nf < 4; ++nf) {
            size_t boff = (size_t)(n0 + nf * 16 + ml) * D + ks * 32 + kq * 8;
            short8 Bh = *(const short8*)(wh + boff);
            short8 Bl = *(const short8*)(wl + boff);
#pragma unroll
            for (int mf = 0; mf < 4; ++mf) {
                acc[mf][nf] = __builtin_amdgcn_mfma_f32_16x16x32_bf16(Ah[mf], Bh, acc[mf][nf], 0, 0, 0);
                acc[mf][nf] = __builtin_amdgcn_mfma_f32_16x16x32_bf16(Ah[mf], Bl, acc[mf][nf], 0, 0, 0);
                acc[mf][nf] = __builtin_amdgcn_mfma_f32_16x16x32_bf16(Al[mf], Bh, acc[mf][nf], 0, 0, 0);
            }
        }
    }

    if (n0 < D) {
#pragma unroll
        for (int nf = 0; nf < 4; ++nf) {
            int col = n0 + nf * 16 + ml;
#pragma unroll
            for (int mf = 0; mf < 4; ++mf) {
                int rbase = m0 + mf * 16 + kq * 4;
#pragma unroll
                for (int r = 0; r < 4; ++r) {
                    int row = rbase + r;
                    if (row < n) yl[(size_t)row * D + col] = f2bf(acc[mf][nf][r]);
                }
            }
        }
    } else {
#pragma unroll
        for (int nf = 0; nf < 4; ++nf) {
            int col = n0 - D + nf * 16 + ml;
            float bv = bias[col];
#pragma unroll
            for (int mf = 0; mf < 4; ++mf) {
                int rbase = m0 + mf * 16 + kq * 4;
#pragma unroll
                for (int r = 0; r < 4; ++r) {
                    int row = rbase + r;
                    if (row < n) out[(size_t)row * D + col] = acc[mf][nf][r] + bv;
                }
            }
        }
    }
}

// ---------------- gather: one wave per node; out[i] += mean of bf16 y_l rows ----------------
__global__ void gather_kernel(const unsigned short* __restrict__ yl,
                              const int* __restrict__ col_sorted,
                              const int* __restrict__ row_start,
                              float* __restrict__ out, int n) {
    int wave = (int)((blockIdx.x * (size_t)blockDim.x + threadIdx.x) >> 6);
    int lane = threadIdx.x & 63;
    if (wave >= n) return;
    int s = row_start[wave];
    int e = row_start[wave + 1];
    float a0 = 0.f, a1 = 0.f;
    int j = s;
    for (; j + 3 < e; j += 4) {
        int c0 = col_sorted[j], c1 = col_sorted[j + 1], c2 = col_sorted[j + 2], c3 = col_sorted[j + 3];
        unsigned v0 = *(const unsigned*)(yl + (size_t)c0 * D + 2 * lane);
        unsigned v1 = *(const unsigned*)(yl + (size_t)c1 * D + 2 * lane);
        unsigned v2 = *(const unsigned*)(yl + (size_t)c2 * D + 2 * lane);
        unsigned v3 = *(const unsigned*)(yl + (size_t)c3 * D + 2 * lane);
        a0 += __uint_as_float(v0 << 16) + __uint_as_float(v1 << 16) +
              __uint_as_float(v2 << 16) + __uint_as_float(v3 << 16);
        a1 += __uint_as_float(v0 & 0xffff0000u) + __uint_as_float(v1 & 0xffff0000u) +
              __uint_as_float(v2 & 0xffff0000u) + __uint_as_float(v3 & 0xffff0000u);
    }
    for (; j < e; ++j) {
        unsigned v = *(const unsigned*)(yl + (size_t)col_sorted[j] * D + 2 * lane);
        a0 += __uint_as_float(v << 16);
        a1 += __uint_as_float(v & 0xffff0000u);
    }
    float inv = (e > s) ? 1.0f / (float)(e - s) : 0.0f;
    float2* po = (float2*)(out + (size_t)wave * D + 2 * lane);
    float2 cur = *po;
    cur.x += a0 * inv;
    cur.y += a1 * inv;
    *po = cur;
}

extern "C" void kernel_launch(void* const* d_in, const int* in_sizes, int n_in,
                              void* d_out, int out_size, void* d_ws, size_t ws_size,
                              hipStream_t stream) {
    const float* x  = (const float*)d_in[0];
    const int*   ei = (const int*)d_in[1];
    const float* Wl = (const float*)d_in[2];
    const float* bl = (const float*)d_in[3];
    const float* Wr = (const float*)d_in[4];
    const float* br = (const float*)d_in[5];
    float* out = (float*)d_out;

    const int n = in_sizes[0] / D;       // 100000
    const int E = in_sizes[1] / 2;       // 1600000

    char* p = (char*)d_ws;
    auto alloc = [&](size_t bytes) {
        char* r = p;
        p += (bytes + 1023) & ~(size_t)1023;
        return r;
    };
    int*   deg        = (int*)alloc((size_t)n * 4);
    int*   cursor     = (int*)alloc((size_t)n * 4);
    int*   row_start  = (int*)alloc((size_t)(n + 1) * 4);
    int*   col_sorted = (int*)alloc((size_t)E * 4);
    int*   partial    = (int*)alloc((size_t)128 * 4);
    unsigned short* wh   = (unsigned short*)alloc((size_t)2 * D * D * 2);
    unsigned short* wlsp = (unsigned short*)alloc((size_t)2 * D * D * 2);
    float* bias       = (float*)alloc((size_t)D * 4);
    unsigned short* xh = (unsigned short*)alloc((size_t)n * D * 2);
    unsigned short* xl = (unsigned short*)alloc((size_t)n * D * 2);
    unsigned short* yl = (unsigned short*)alloc((size_t)n * D * 2);

    hipMemsetAsync(deg, 0, (size_t)n * 4, stream);

    const int nb = (n + 1023) / 1024;    // 98 chunks
    int n4 = n * D / 4;
    split_kernel<<<(n4 + 255) / 256, 256, 0, stream>>>((const float4*)x, (uint2*)xh, (uint2*)xl, n4);
    prepw_kernel<<<(2 * D * D + 255) / 256, 256, 0, stream>>>(Wl, bl, Wr, br, wh, wlsp, bias);
    deg_kernel<<<(E + 255) / 256, 256, 0, stream>>>(ei, deg, E);
    partial_kernel<<<nb, 256, 0, stream>>>(deg, partial, n);
    scanp_kernel<<<1, 128, 0, stream>>>(partial, row_start, nb, n);
    scanf_kernel<<<nb, 256, 0, stream>>>(deg, partial, row_start, cursor, n);
    bucket_kernel<<<(E + 255) / 256, 256, 0, stream>>>(ei, cursor, col_sorted, E);
    mm_kernel<<<(n + 63) / 64, 256, 0, stream>>>(xh, xl, wh, wlsp, bias, yl, out, n);
    gather_kernel<<<(n * 64 + 255) / 256, 256, 0, stream>>>(yl, col_sorted, row_start, out, n);
}

// Round 4
// 445.342 us; speedup vs baseline: 1.6689x; 1.0719x over previous
//
#include <hip/hip_runtime.h>

#define D 128
#define NPB 128          // nodes per bucket (row >> 7)
#define NSB 8            // sub-buckets (blockIdx residue ~ XCD)
#define CAP 512          // capacity per sub-bucket (avg 256, 16 sigma headroom)

typedef __attribute__((ext_vector_type(8))) short short8;
typedef __attribute__((ext_vector_type(4))) float f32x4;

__device__ __forceinline__ unsigned short f2bf(float f) {
    unsigned u = __float_as_uint(f);
    return (unsigned short)((u + 0x7fffu + ((u >> 16) & 1u)) >> 16);
}

// ---------------- split x into bf16 hi + bf16 lo(residual) ----------------
__global__ void split_kernel(const float4* __restrict__ x, uint2* __restrict__ xh,
                             uint2* __restrict__ xl, int n4) {
    int i = blockIdx.x * blockDim.x + threadIdx.x;
    if (i >= n4) return;
    float4 v = x[i];
    unsigned short h0 = f2bf(v.x), h1 = f2bf(v.y), h2 = f2bf(v.z), h3 = f2bf(v.w);
    float r0 = v.x - __uint_as_float((unsigned)h0 << 16);
    float r1 = v.y - __uint_as_float((unsigned)h1 << 16);
    float r2 = v.z - __uint_as_float((unsigned)h2 << 16);
    float r3 = v.w - __uint_as_float((unsigned)h3 << 16);
    unsigned short l0 = f2bf(r0), l1 = f2bf(r1), l2 = f2bf(r2), l3 = f2bf(r3);
    uint2 hh, ll;
    hh.x = (unsigned)h0 | ((unsigned)h1 << 16);
    hh.y = (unsigned)h2 | ((unsigned)h3 << 16);
    ll.x = (unsigned)l0 | ((unsigned)l1 << 16);
    ll.y = (unsigned)l2 | ((unsigned)l3 << 16);
    xh[i] = hh;
    xl[i] = ll;
}

// ---------------- weight prep ----------------
__global__ void prepw_kernel(const float* __restrict__ Wl_in, const float* __restrict__ bl,
                             const float* __restrict__ Wr_in, const float* __restrict__ br,
                             unsigned short* __restrict__ wh, unsigned short* __restrict__ wl,
                             float* __restrict__ bias) {
    int t = blockIdx.x * blockDim.x + threadIdx.x;
    if (t < 2 * D * D) {
        int n = t >> 7;
        int k = t & (D - 1);
        float v = (n < D) ? Wl_in[n * D + k] : Wr_in[(n - D) * D + k];
        unsigned short h = f2bf(v);
        float r = v - __uint_as_float((unsigned)h << 16);
        wh[t] = h;
        wl[t] = f2bf(r);
    }
    if (t < D) bias[t] = bl[t] + br[t];
}

// ---------------- phase A: partition edges into bucket x sub-bucket append streams ----------------
__global__ __launch_bounds__(256) void part_kernel(const int* __restrict__ ei,
                                                   int* __restrict__ bcnt,
                                                   uint2* __restrict__ pairs, int E) {
    int e = blockIdx.x * 256 + threadIdx.x;
    if (e >= E) return;
    int r = ei[e];
    int c = ei[E + e];
    int sb = (r >> 7) * NSB + (blockIdx.x & (NSB - 1));
    int slot = atomicAdd(&bcnt[sb], 1);
    if (slot < CAP) {
        uint2 q; q.x = (unsigned)r; q.y = (unsigned)c;
        pairs[(size_t)sb * CAP + slot] = q;
    }
}

// ---------------- phase B0: exclusive scan of bucket totals ----------------
__global__ void scanb_kernel(const int* __restrict__ bcnt, int* __restrict__ bbase,
                             int* __restrict__ row_start, int nbk, int n) {
    __shared__ int s[1024];
    int t = threadIdx.x;
    int v = 0;
    if (t < nbk) {
        int4 a = *(const int4*)(bcnt + t * NSB);
        int4 b = *(const int4*)(bcnt + t * NSB + 4);
        v = a.x + a.y + a.z + a.w + b.x + b.y + b.z + b.w;
    }
    s[t] = v;
    __syncthreads();
    for (int off = 1; off < 1024; off <<= 1) {
        int u = (t >= off) ? s[t - off] : 0;
        __syncthreads();
        s[t] += u;
        __syncthreads();
    }
    if (t < nbk) bbase[t] = s[t] - v;
    if (t == 1023) row_start[n] = s[1023];
}

// ---------------- phase B: per-bucket LDS histogram + scan + place ----------------
__global__ __launch_bounds__(256) void place_kernel(const int* __restrict__ bcnt,
                                                    const int* __restrict__ bbase,
                                                    const uint2* __restrict__ pairs,
                                                    int* __restrict__ row_start,
                                                    int* __restrict__ col_sorted, int n) {
    __shared__ int hist[NPB];
    __shared__ int pre[NPB];
    __shared__ int cnts[NSB];
    int b = blockIdx.x, t = threadIdx.x;
    if (t < NPB) hist[t] = 0;
    if (t < NSB) cnts[t] = bcnt[b * NSB + t];
    __syncthreads();
    // pass 1: histogram rows
    for (int sb = 0; sb < NSB; ++sb) {
        int cnt = cnts[sb];
        const uint2* pp = pairs + (size_t)(b * NSB + sb) * CAP;
        for (int i = t; i < cnt; i += 256)
            atomicAdd(&hist[pp[i].x & (NPB - 1)], 1);
    }
    __syncthreads();
    if (t < NPB) pre[t] = hist[t];
    __syncthreads();
    for (int off = 1; off < NPB; off <<= 1) {
        int u = (t >= off && t < NPB) ? pre[t - off] : 0;
        __syncthreads();
        if (t < NPB) pre[t] += u;
        __syncthreads();
    }
    int base = bbase[b];
    if (t < NPB) {
        int ex = pre[t] - hist[t];            // exclusive prefix
        int node = b * NPB + t;
        if (node < n) row_start[node] = base + ex;
        hist[t] = ex;                          // reuse as cursor
    }
    __syncthreads();
    // pass 2: place cols into contiguous window
    for (int sb = 0; sb < NSB; ++sb) {
        int cnt = cnts[sb];
        const uint2* pp = pairs + (size_t)(b * NSB + sb) * CAP;
        for (int i = t; i < cnt; i += 256) {
            uint2 p = pp[i];
            int slot = atomicAdd(&hist[p.x & (NPB - 1)], 1);
            col_sorted[base + slot] = (int)p.y;
        }
    }
}

// ---------------- bf16x3 MFMA GEMM: [y_l | out] = x @ [W_l ; W_r]^T (+bias on out half) ----------------
__global__ __launch_bounds__(256) void mm_kernel(const unsigned short* __restrict__ xh,
                                                 const unsigned short* __restrict__ xl,
                                                 const unsigned short* __restrict__ wh,
                                                 const unsigned short* __restrict__ wl,
                                                 const float* __restrict__ bias,
                                                 unsigned short* __restrict__ yl,
                                                 float* __restrict__ out, int n) {
    int w = threadIdx.x >> 6;
    int l = threadIdx.x & 63;
    int ml = l & 15;
    int kq = l >> 4;
    int m0 = blockIdx.x * 64;
    int n0 = w * 64;

    f32x4 acc[4][4];
#pragma unroll
    for (int a = 0; a < 4; ++a)
#pragma unroll
        for (int b = 0; b < 4; ++b) acc[a][b] = (f32x4){0.f, 0.f, 0.f, 0.f};

#pragma unroll
    for (int ks = 0; ks < 4; ++ks) {
        short8 Ah[4], Al[4];
#pragma unroll
        for (int mf = 0; mf < 4; ++mf) {
            int row = m0 + mf * 16 + ml;
            if (row > n - 1) row = n - 1;
            size_t off = (size_t)row * D + ks * 32 + kq * 8;
            Ah[mf] = *(const short8*)(xh + off);
            Al[mf] = *(const short8*)(xl + off);
        }
#pragma unroll
        for (int nf = 0; nf < 4; ++nf) {
            size_t boff = (size_t)(n0 + nf * 16 + ml) * D + ks * 32 + kq * 8;
            short8 Bh = *(const short8*)(wh + boff);
            short8 Bl = *(const short8*)(wl + boff);
#pragma unroll
            for (int mf = 0; mf < 4; ++mf) {
                acc[mf][nf] = __builtin_amdgcn_mfma_f32_16x16x32_bf16(Ah[mf], Bh, acc[mf][nf], 0, 0, 0);
                acc[mf][nf] = __builtin_amdgcn_mfma_f32_16x16x32_bf16(Ah[mf], Bl, acc[mf][nf], 0, 0, 0);
                acc[mf][nf] = __builtin_amdgcn_mfma_f32_16x16x32_bf16(Al[mf], Bh, acc[mf][nf], 0, 0, 0);
            }
        }
    }

    if (n0 < D) {
#pragma unroll
        for (int nf = 0; nf < 4; ++nf) {
            int col = n0 + nf * 16 + ml;
#pragma unroll
            for (int mf = 0; mf < 4; ++mf) {
                int rbase = m0 + mf * 16 + kq * 4;
#pragma unroll
                for (int r = 0; r < 4; ++r) {
                    int row = rbase + r;
                    if (row < n) yl[(size_t)row * D + col] = f2bf(acc[mf][nf][r]);
                }
            }
        }
    } else {
#pragma unroll
        for (int nf = 0; nf < 4; ++nf) {
            int col = n0 - D + nf * 16 + ml;
            float bv = bias[col];
#pragma unroll
            for (int mf = 0; mf < 4; ++mf) {
                int rbase = m0 + mf * 16 + kq * 4;
#pragma unroll
                for (int r = 0; r < 4; ++r) {
                    int row = rbase + r;
                    if (row < n) out[(size_t)row * D + col] = acc[mf][nf][r] + bv;
                }
            }
        }
    }
}

// ---------------- gather: one wave per node; out[i] += mean of bf16 y_l rows ----------------
__global__ void gather_kernel(const unsigned short* __restrict__ yl,
                              const int* __restrict__ col_sorted,
                              const int* __restrict__ row_start,
                              float* __restrict__ out, int n) {
    int wave = (int)((blockIdx.x * (size_t)blockDim.x + threadIdx.x) >> 6);
    int lane = threadIdx.x & 63;
    if (wave >= n) return;
    int s = row_start[wave];
    int e = row_start[wave + 1];
    float a0 = 0.f, a1 = 0.f;
    int j = s;
    for (; j + 3 < e; j += 4) {
        int c0 = col_sorted[j], c1 = col_sorted[j + 1], c2 = col_sorted[j + 2], c3 = col_sorted[j + 3];
        unsigned v0 = *(const unsigned*)(yl + (size_t)c0 * D + 2 * lane);
        unsigned v1 = *(const unsigned*)(yl + (size_t)c1 * D + 2 * lane);
        unsigned v2 = *(const unsigned*)(yl + (size_t)c2 * D + 2 * lane);
        unsigned v3 = *(const unsigned*)(yl + (size_t)c3 * D + 2 * lane);
        a0 += __uint_as_float(v0 << 16) + __uint_as_float(v1 << 16) +
              __uint_as_float(v2 << 16) + __uint_as_float(v3 << 16);
        a1 += __uint_as_float(v0 & 0xffff0000u) + __uint_as_float(v1 & 0xffff0000u) +
              __uint_as_float(v2 & 0xffff0000u) + __uint_as_float(v3 & 0xffff0000u);
    }
    for (; j < e; ++j) {
        unsigned v = *(const unsigned*)(yl + (size_t)col_sorted[j] * D + 2 * lane);
        a0 += __uint_as_float(v << 16);
        a1 += __uint_as_float(v & 0xffff0000u);
    }
    float inv = (e > s) ? 1.0f / (float)(e - s) : 0.0f;
    float2* po = (float2*)(out + (size_t)wave * D + 2 * lane);
    float2 cur = *po;
    cur.x += a0 * inv;
    cur.y += a1 * inv;
    *po = cur;
}

extern "C" void kernel_launch(void* const* d_in, const int* in_sizes, int n_in,
                              void* d_out, int out_size, void* d_ws, size_t ws_size,
                              hipStream_t stream) {
    const float* x  = (const float*)d_in[0];
    const int*   ei = (const int*)d_in[1];
    const float* Wl = (const float*)d_in[2];
    const float* bl = (const float*)d_in[3];
    const float* Wr = (const float*)d_in[4];
    const float* br = (const float*)d_in[5];
    float* out = (float*)d_out;

    const int n = in_sizes[0] / D;       // 100000
    const int E = in_sizes[1] / 2;       // 1600000
    const int nbk = (n + NPB - 1) / NPB; // 782 buckets

    char* p = (char*)d_ws;
    auto alloc = [&](size_t bytes) {
        char* r = p;
        p += (bytes + 1023) & ~(size_t)1023;
        return r;
    };
    int*   row_start  = (int*)alloc((size_t)(n + 1) * 4);
    int*   col_sorted = (int*)alloc((size_t)E * 4);
    int*   bcnt       = (int*)alloc((size_t)nbk * NSB * 4);
    int*   bbase      = (int*)alloc((size_t)nbk * 4);
    unsigned short* wh   = (unsigned short*)alloc((size_t)2 * D * D * 2);
    unsigned short* wlsp = (unsigned short*)alloc((size_t)2 * D * D * 2);
    float* bias       = (float*)alloc((size_t)D * 4);
    unsigned short* xh = (unsigned short*)alloc((size_t)n * D * 2);
    unsigned short* xl = (unsigned short*)alloc((size_t)n * D * 2);
    unsigned short* yl = (unsigned short*)alloc((size_t)n * D * 2);
    uint2* pairs = (uint2*)yl;   // alias: pairs lifetime (part..place) disjoint from yl (mm..gather)
    // pairs needs nbk*NSB*CAP*8 = 25.6 MB == yl size; assert fits
    // (782*8*512*8 = 25,624,576 <= 100000*128*2 = 25,600,000) -> NOT quite! use xh? same size issue.
    // Allocate pairs separately to be safe:
    pairs = (uint2*)alloc((size_t)nbk * NSB * CAP * 8);

    hipMemsetAsync(bcnt, 0, (size_t)nbk * NSB * 4, stream);

    int n4 = n * D / 4;
    split_kernel<<<(n4 + 255) / 256, 256, 0, stream>>>((const float4*)x, (uint2*)xh, (uint2*)xl, n4);
    prepw_kernel<<<(2 * D * D + 255) / 256, 256, 0, stream>>>(Wl, bl, Wr, br, wh, wlsp, bias);
    part_kernel<<<(E + 255) / 256, 256, 0, stream>>>(ei, bcnt, pairs, E);
    scanb_kernel<<<1, 1024, 0, stream>>>(bcnt, bbase, row_start, nbk, n);
    place_kernel<<<nbk, 256, 0, stream>>>(bcnt, bbase, pairs, row_start, col_sorted, n);
    mm_kernel<<<(n + 63) / 64, 256, 0, stream>>>(xh, xl, wh, wlsp, bias, yl, out, n);
    gather_kernel<<<(n * 64 + 255) / 256, 256, 0, stream>>>(yl, col_sorted, row_start, out, n);
}

// Round 6
// 335.007 us; speedup vs baseline: 2.2185x; 1.3294x over previous
//
#include <hip/hip_runtime.h>

#define D 128
#define NPB 128          // nodes per bucket (row >> 7)
#define MAXBK 800        // max buckets (n <= 102400)
#define NBLK 256         // partition grid (hist/scatter), also cnt stride

typedef __attribute__((ext_vector_type(8))) short short8;
typedef __attribute__((ext_vector_type(4))) float f32x4;

__device__ __forceinline__ unsigned short f2bf(float f) {
    unsigned u = __float_as_uint(f);
    return (unsigned short)((u + 0x7fffu + ((u >> 16) & 1u)) >> 16);
}

// ---------------- split x into bf16 hi + bf16 lo(residual) ----------------
__global__ void split_kernel(const float4* __restrict__ x, uint2* __restrict__ xh,
                             uint2* __restrict__ xl, int n4) {
    int i = blockIdx.x * blockDim.x + threadIdx.x;
    if (i >= n4) return;
    float4 v = x[i];
    unsigned short h0 = f2bf(v.x), h1 = f2bf(v.y), h2 = f2bf(v.z), h3 = f2bf(v.w);
    float r0 = v.x - __uint_as_float((unsigned)h0 << 16);
    float r1 = v.y - __uint_as_float((unsigned)h1 << 16);
    float r2 = v.z - __uint_as_float((unsigned)h2 << 16);
    float r3 = v.w - __uint_as_float((unsigned)h3 << 16);
    unsigned short l0 = f2bf(r0), l1 = f2bf(r1), l2 = f2bf(r2), l3 = f2bf(r3);
    uint2 hh, ll;
    hh.x = (unsigned)h0 | ((unsigned)h1 << 16);
    hh.y = (unsigned)h2 | ((unsigned)h3 << 16);
    ll.x = (unsigned)l0 | ((unsigned)l1 << 16);
    ll.y = (unsigned)l2 | ((unsigned)l3 << 16);
    xh[i] = hh;
    xl[i] = ll;
}

// ---------------- weight prep ----------------
__global__ void prepw_kernel(const float* __restrict__ Wl_in, const float* __restrict__ bl,
                             const float* __restrict__ Wr_in, const float* __restrict__ br,
                             unsigned short* __restrict__ wh, unsigned short* __restrict__ wl,
                             float* __restrict__ bias) {
    int t = blockIdx.x * blockDim.x + threadIdx.x;
    if (t < 2 * D * D) {
        int n = t >> 7;
        int k = t & (D - 1);
        float v = (n < D) ? Wl_in[n * D + k] : Wr_in[(n - D) * D + k];
        unsigned short h = f2bf(v);
        float r = v - __uint_as_float((unsigned)h << 16);
        wh[t] = h;
        wl[t] = f2bf(r);
    }
    if (t < D) bias[t] = bl[t] + br[t];
}

// ---------------- pass 1: per-block LDS histogram by bucket ----------------
__global__ __launch_bounds__(256) void hist_kernel(const int* __restrict__ ei,
                                                   int* __restrict__ cnt,
                                                   int E, int nbk, int chunk) {
    __shared__ int h[MAXBK];
    int b = blockIdx.x, t = threadIdx.x;
    for (int i = t; i < nbk; i += 256) h[i] = 0;
    __syncthreads();
    int lo = b * chunk, hi = min(E, lo + chunk);
    for (int e = lo + t; e < hi; e += 256)
        atomicAdd(&h[ei[e] >> 7], 1);
    __syncthreads();
    for (int i = t; i < nbk; i += 256) cnt[i * NBLK + b] = h[i];
}

// ---------------- pass 2a: exclusive scan of each bucket's 256 block-counts ----------------
__global__ __launch_bounds__(256) void scan_cnt_kernel(int* __restrict__ cnt,
                                                       int* __restrict__ btot) {
    int b = blockIdx.x, t = threadIdx.x;
    int lane = t & 63, w = t >> 6;
    int v = cnt[b * NBLK + t];
    int s = v;
    for (int off = 1; off < 64; off <<= 1) {
        int u = __shfl_up(s, off, 64);
        if (lane >= off) s += u;
    }
    __shared__ int wsum[4], woff[4];
    if (lane == 63) wsum[w] = s;
    __syncthreads();
    if (t == 0) {
        int run = 0;
        for (int i = 0; i < 4; ++i) { woff[i] = run; run += wsum[i]; }
        btot[b] = run;
    }
    __syncthreads();
    cnt[b * NBLK + t] = s - v + woff[w];   // exclusive prefix within bucket
}

// ---------------- pass 2b: exclusive scan of bucket totals ----------------
__global__ void scan_btot_kernel(const int* __restrict__ btot, int* __restrict__ bbase,
                                 int* __restrict__ row_start, int nbk, int n) {
    __shared__ int s[1024];
    int t = threadIdx.x;
    int v = (t < nbk) ? btot[t] : 0;
    s[t] = v;
    __syncthreads();
    for (int off = 1; off < 1024; off <<= 1) {
        int u = (t >= off) ? s[t - off] : 0;
        __syncthreads();
        s[t] += u;
        __syncthreads();
    }
    if (t < nbk) bbase[t] = s[t] - v;
    if (t == 1023) { bbase[nbk] = s[1023]; row_start[n] = s[1023]; }
}

// ---------------- pass 3: scatter packed (row&127)<<17|col into per-(block,bucket) regions ----------------
__global__ __launch_bounds__(256) void scatter_kernel(const int* __restrict__ ei,
                                                      const int* __restrict__ cnt,
                                                      const int* __restrict__ bbase,
                                                      unsigned* __restrict__ pk,
                                                      int E, int nbk, int chunk) {
    __shared__ int curs[MAXBK];
    int b = blockIdx.x, t = threadIdx.x;
    for (int i = t; i < nbk; i += 256) curs[i] = bbase[i] + cnt[i * NBLK + b];
    __syncthreads();
    int lo = b * chunk, hi = min(E, lo + chunk);
    for (int e = lo + t; e < hi; e += 256) {
        int r = ei[e];
        int c = ei[E + e];
        int pos = atomicAdd(&curs[r >> 7], 1);
        pk[pos] = ((unsigned)(r & (NPB - 1)) << 17) | (unsigned)c;
    }
}

// ---------------- per-bucket: histogram rows -> row_start; place cols ----------------
__global__ __launch_bounds__(256) void place_kernel(const int* __restrict__ bbase,
                                                    const unsigned* __restrict__ pk,
                                                    int* __restrict__ row_start,
                                                    int* __restrict__ col_sorted, int n) {
    __shared__ int hist[NPB];
    __shared__ int pre[NPB];
    int b = blockIdx.x, t = threadIdx.x;
    if (t < NPB) hist[t] = 0;
    __syncthreads();
    int s0 = bbase[b], e0 = bbase[b + 1];
    for (int i = s0 + t; i < e0; i += 256)
        atomicAdd(&hist[pk[i] >> 17], 1);
    __syncthreads();
    if (t < NPB) pre[t] = hist[t];
    __syncthreads();
    for (int off = 1; off < NPB; off <<= 1) {
        int u = (t >= off && t < NPB) ? pre[t - off] : 0;
        __syncthreads();
        if (t < NPB) pre[t] += u;
        __syncthreads();
    }
    if (t < NPB) {
        int ex = pre[t] - hist[t];
        int node = b * NPB + t;
        if (node < n) row_start[node] = s0 + ex;
        hist[t] = ex;                   // reuse as cursor
    }
    __syncthreads();
    for (int i = s0 + t; i < e0; i += 256) {
        unsigned p = pk[i];
        int slot = atomicAdd(&hist[p >> 17], 1);
        col_sorted[s0 + slot] = (int)(p & 0x1FFFFu);
    }
}

// ---------------- bf16x3 MFMA GEMM: [y_l | out] = x @ [W_l ; W_r]^T (+bias on out half) ----------------
__global__ __launch_bounds__(256) void mm_kernel(const unsigned short* __restrict__ xh,
                                                 const unsigned short* __restrict__ xl,
                                                 const unsigned short* __restrict__ wh,
                                                 const unsigned short* __restrict__ wl,
                                                 const float* __restrict__ bias,
                                                 unsigned short* __restrict__ yl,
                                                 float* __restrict__ out, int n) {
    int w = threadIdx.x >> 6;
    int l = threadIdx.x & 63;
    int ml = l & 15;
    int kq = l >> 4;
    int m0 = blockIdx.x * 64;
    int n0 = w * 64;

    f32x4 acc[4][4];
#pragma unroll
    for (int a = 0; a < 4; ++a)
#pragma unroll
        for (int b = 0; b < 4; ++b) acc[a][b] = (f32x4){0.f, 0.f, 0.f, 0.f};

#pragma unroll
    for (int ks = 0; ks < 4; ++ks) {
        short8 Ah[4], Al[4];
#pragma unroll
        for (int mf = 0; mf < 4; ++mf) {
            int row = m0 + mf * 16 + ml;
            if (row > n - 1) row = n - 1;
            size_t off = (size_t)row * D + ks * 32 + kq * 8;
            Ah[mf] = *(const short8*)(xh + off);
            Al[mf] = *(const short8*)(xl + off);
        }
#pragma unroll
        for (int nf = 0; nf < 4; ++nf) {
            size_t boff = (size_t)(n0 + nf * 16 + ml) * D + ks * 32 + kq * 8;
            short8 Bh = *(const short8*)(wh + boff);
            short8 Bl = *(const short8*)(wl + boff);
#pragma unroll
            for (int mf = 0; mf < 4; ++mf) {
                acc[mf][nf] = __builtin_amdgcn_mfma_f32_16x16x32_bf16(Ah[mf], Bh, acc[mf][nf], 0, 0, 0);
                acc[mf][nf] = __builtin_amdgcn_mfma_f32_16x16x32_bf16(Ah[mf], Bl, acc[mf][nf], 0, 0, 0);
                acc[mf][nf] = __builtin_amdgcn_mfma_f32_16x16x32_bf16(Al[mf], Bh, acc[mf][nf], 0, 0, 0);
            }
        }
    }

    if (n0 < D) {
#pragma unroll
        for (int nf = 0; nf < 4; ++nf) {
            int col = n0 + nf * 16 + ml;
#pragma unroll
            for (int mf = 0; mf < 4; ++mf) {
                int rbase = m0 + mf * 16 + kq * 4;
#pragma unroll
                for (int r = 0; r < 4; ++r) {
                    int row = rbase + r;
                    if (row < n) yl[(size_t)row * D + col] = f2bf(acc[mf][nf][r]);
                }
            }
        }
    } else {
#pragma unroll
        for (int nf = 0; nf < 4; ++nf) {
            int col = n0 - D + nf * 16 + ml;
            float bv = bias[col];
#pragma unroll
            for (int mf = 0; mf < 4; ++mf) {
                int rbase = m0 + mf * 16 + kq * 4;
#pragma unroll
                for (int r = 0; r < 4; ++r) {
                    int row = rbase + r;
                    if (row < n) out[(size_t)row * D + col] = acc[mf][nf][r] + bv;
                }
            }
        }
    }
}

// ---------------- gather: one wave per node; out[i] += mean of bf16 y_l rows ----------------
__global__ void gather_kernel(const unsigned short* __restrict__ yl,
                              const int* __restrict__ col_sorted,
                              const int* __restrict__ row_start,
                              float* __restrict__ out, int n) {
    int wave = (int)((blockIdx.x * (size_t)blockDim.x + threadIdx.x) >> 6);
    int lane = threadIdx.x & 63;
    if (wave >= n) return;
    int s = row_start[wave];
    int e = row_start[wave + 1];
    float a0 = 0.f, a1 = 0.f;
    int j = s;
    for (; j + 3 < e; j += 4) {
        int c0 = col_sorted[j], c1 = col_sorted[j + 1], c2 = col_sorted[j + 2], c3 = col_sorted[j + 3];
        unsigned v0 = *(const unsigned*)(yl + (size_t)c0 * D + 2 * lane);
        unsigned v1 = *(const unsigned*)(yl + (size_t)c1 * D + 2 * lane);
        unsigned v2 = *(const unsigned*)(yl + (size_t)c2 * D + 2 * lane);
        unsigned v3 = *(const unsigned*)(yl + (size_t)c3 * D + 2 * lane);
        a0 += __uint_as_float(v0 << 16) + __uint_as_float(v1 << 16) +
              __uint_as_float(v2 << 16) + __uint_as_float(v3 << 16);
        a1 += __uint_as_float(v0 & 0xffff0000u) + __uint_as_float(v1 & 0xffff0000u) +
              __uint_as_float(v2 & 0xffff0000u) + __uint_as_float(v3 & 0xffff0000u);
    }
    for (; j < e; ++j) {
        unsigned v = *(const unsigned*)(yl + (size_t)col_sorted[j] * D + 2 * lane);
        a0 += __uint_as_float(v << 16);
        a1 += __uint_as_float(v & 0xffff0000u);
    }
    float inv = (e > s) ? 1.0f / (float)(e - s) : 0.0f;
    float2* po = (float2*)(out + (size_t)wave * D + 2 * lane);
    float2 cur = *po;
    cur.x += a0 * inv;
    cur.y += a1 * inv;
    *po = cur;
}

extern "C" void kernel_launch(void* const* d_in, const int* in_sizes, int n_in,
                              void* d_out, int out_size, void* d_ws, size_t ws_size,
                              hipStream_t stream) {
    const float* x  = (const float*)d_in[0];
    const int*   ei = (const int*)d_in[1];
    const float* Wl = (const float*)d_in[2];
    const float* bl = (const float*)d_in[3];
    const float* Wr = (const float*)d_in[4];
    const float* br = (const float*)d_in[5];
    float* out = (float*)d_out;

    const int n = in_sizes[0] / D;       // 100000
    const int E = in_sizes[1] / 2;       // 1600000
    const int nbk = (n + NPB - 1) / NPB; // 782 buckets (<= MAXBK)
    const int chunk = (E + NBLK - 1) / NBLK;

    char* p = (char*)d_ws;
    auto alloc = [&](size_t bytes) {
        char* r = p;
        p += (bytes + 1023) & ~(size_t)1023;
        return r;
    };
    int*   row_start  = (int*)alloc((size_t)(n + 1) * 4);
    int*   col_sorted = (int*)alloc((size_t)E * 4);
    int*   cnt        = (int*)alloc((size_t)nbk * NBLK * 4);
    int*   btot       = (int*)alloc((size_t)nbk * 4);
    int*   bbase      = (int*)alloc((size_t)(nbk + 1) * 4);
    unsigned* pk      = (unsigned*)alloc((size_t)E * 4);
    unsigned short* wh   = (unsigned short*)alloc((size_t)2 * D * D * 2);
    unsigned short* wlsp = (unsigned short*)alloc((size_t)2 * D * D * 2);
    float* bias       = (float*)alloc((size_t)D * 4);
    unsigned short* xh = (unsigned short*)alloc((size_t)n * D * 2);
    unsigned short* xl = (unsigned short*)alloc((size_t)n * D * 2);
    unsigned short* yl = (unsigned short*)alloc((size_t)n * D * 2);

    int n4 = n * D / 4;
    split_kernel<<<(n4 + 255) / 256, 256, 0, stream>>>((const float4*)x, (uint2*)xh, (uint2*)xl, n4);
    prepw_kernel<<<(2 * D * D + 255) / 256, 256, 0, stream>>>(Wl, bl, Wr, br, wh, wlsp, bias);
    hist_kernel<<<NBLK, 256, 0, stream>>>(ei, cnt, E, nbk, chunk);
    scan_cnt_kernel<<<nbk, 256, 0, stream>>>(cnt, btot);
    scan_btot_kernel<<<1, 1024, 0, stream>>>(btot, bbase, row_start, nbk, n);
    scatter_kernel<<<NBLK, 256, 0, stream>>>(ei, cnt, bbase, pk, E, nbk, chunk);
    place_kernel<<<nbk, 256, 0, stream>>>(bbase, pk, row_start, col_sorted, n);
    mm_kernel<<<(n + 63) / 64, 256, 0, stream>>>(xh, xl, wh, wlsp, bias, yl, out, n);
    gather_kernel<<<(n * 64 + 255) / 256, 256, 0, stream>>>(yl, col_sorted, row_start, out, n);
}

// Round 7
// 278.691 us; speedup vs baseline: 2.6668x; 1.2021x over previous
//
#include <hip/hip_runtime.h>

#define D 128
#define NPB 128          // nodes per bucket (row >> 7)
#define MAXBK 800        // max buckets (n <= 102400)
#define NBLK 256         // partition grid (hist/scatter), also cnt stride

typedef __attribute__((ext_vector_type(8))) short short8;
typedef __attribute__((ext_vector_type(4))) float f32x4;

__device__ __forceinline__ unsigned short f2bf(float f) {
    unsigned u = __float_as_uint(f);
    return (unsigned short)((u + 0x7fffu + ((u >> 16) & 1u)) >> 16);
}

// ---------------- weight prep: rows 0..127 = W_l, 128..255 = W_r, split hi/lo; bias = b_l+b_r ----------------
__global__ void prepw_kernel(const float* __restrict__ Wl_in, const float* __restrict__ bl,
                             const float* __restrict__ Wr_in, const float* __restrict__ br,
                             unsigned short* __restrict__ wh, unsigned short* __restrict__ wl,
                             float* __restrict__ bias) {
    int t = blockIdx.x * blockDim.x + threadIdx.x;
    if (t < 2 * D * D) {
        int n = t >> 7;
        int k = t & (D - 1);
        float v = (n < D) ? Wl_in[n * D + k] : Wr_in[(n - D) * D + k];
        unsigned short h = f2bf(v);
        float r = v - __uint_as_float((unsigned)h << 16);
        wh[t] = h;
        wl[t] = f2bf(r);
    }
    if (t < D) bias[t] = bl[t] + br[t];
}

// ---------------- pass 1: per-block LDS histogram by bucket ----------------
__global__ __launch_bounds__(256) void hist_kernel(const int* __restrict__ ei,
                                                   int* __restrict__ cnt,
                                                   int E, int nbk, int chunk) {
    __shared__ int h[MAXBK];
    int b = blockIdx.x, t = threadIdx.x;
    for (int i = t; i < nbk; i += 256) h[i] = 0;
    __syncthreads();
    int lo = b * chunk, hi = min(E, lo + chunk);
    for (int e = lo + t; e < hi; e += 256)
        atomicAdd(&h[ei[e] >> 7], 1);
    __syncthreads();
    for (int i = t; i < nbk; i += 256) cnt[i * NBLK + b] = h[i];
}

// ---------------- pass 2a: exclusive scan of each bucket's 256 block-counts ----------------
__global__ __launch_bounds__(256) void scan_cnt_kernel(int* __restrict__ cnt,
                                                       int* __restrict__ btot) {
    int b = blockIdx.x, t = threadIdx.x;
    int lane = t & 63, w = t >> 6;
    int v = cnt[b * NBLK + t];
    int s = v;
    for (int off = 1; off < 64; off <<= 1) {
        int u = __shfl_up(s, off, 64);
        if (lane >= off) s += u;
    }
    __shared__ int wsum[4], woff[4];
    if (lane == 63) wsum[w] = s;
    __syncthreads();
    if (t == 0) {
        int run = 0;
        for (int i = 0; i < 4; ++i) { woff[i] = run; run += wsum[i]; }
        btot[b] = run;
    }
    __syncthreads();
    cnt[b * NBLK + t] = s - v + woff[w];   // exclusive prefix within bucket
}

// ---------------- pass 2b: exclusive scan of bucket totals ----------------
__global__ void scan_btot_kernel(const int* __restrict__ btot, int* __restrict__ bbase,
                                 int* __restrict__ row_start, int nbk, int n) {
    __shared__ int s[1024];
    int t = threadIdx.x;
    int v = (t < nbk) ? btot[t] : 0;
    s[t] = v;
    __syncthreads();
    for (int off = 1; off < 1024; off <<= 1) {
        int u = (t >= off) ? s[t - off] : 0;
        __syncthreads();
        s[t] += u;
        __syncthreads();
    }
    if (t < nbk) bbase[t] = s[t] - v;
    if (t == 1023) { bbase[nbk] = s[1023]; row_start[n] = s[1023]; }
}

// ---------------- pass 3: scatter packed (row&127)<<17|col into per-(block,bucket) regions ----------------
__global__ __launch_bounds__(256) void scatter_kernel(const int* __restrict__ ei,
                                                      const int* __restrict__ cnt,
                                                      const int* __restrict__ bbase,
                                                      unsigned* __restrict__ pk,
                                                      int E, int nbk, int chunk) {
    __shared__ int curs[MAXBK];
    int b = blockIdx.x, t = threadIdx.x;
    for (int i = t; i < nbk; i += 256) curs[i] = bbase[i] + cnt[i * NBLK + b];
    __syncthreads();
    int lo = b * chunk, hi = min(E, lo + chunk);
    for (int e = lo + t; e < hi; e += 256) {
        int r = ei[e];
        int c = ei[E + e];
        int pos = atomicAdd(&curs[r >> 7], 1);
        pk[pos] = ((unsigned)(r & (NPB - 1)) << 17) | (unsigned)c;
    }
}

// ---------------- per-bucket: histogram rows -> row_start; place cols ----------------
__global__ __launch_bounds__(256) void place_kernel(const int* __restrict__ bbase,
                                                    const unsigned* __restrict__ pk,
                                                    int* __restrict__ row_start,
                                                    int* __restrict__ col_sorted, int n) {
    __shared__ int hist[NPB];
    __shared__ int pre[NPB];
    int b = blockIdx.x, t = threadIdx.x;
    if (t < NPB) hist[t] = 0;
    __syncthreads();
    int s0 = bbase[b], e0 = bbase[b + 1];
    for (int i = s0 + t; i < e0; i += 256)
        atomicAdd(&hist[pk[i] >> 17], 1);
    __syncthreads();
    if (t < NPB) pre[t] = hist[t];
    __syncthreads();
    for (int off = 1; off < NPB; off <<= 1) {
        int u = (t >= off && t < NPB) ? pre[t - off] : 0;
        __syncthreads();
        if (t < NPB) pre[t] += u;
        __syncthreads();
    }
    if (t < NPB) {
        int ex = pre[t] - hist[t];
        int node = b * NPB + t;
        if (node < n) row_start[node] = s0 + ex;
        hist[t] = ex;                   // reuse as cursor
    }
    __syncthreads();
    for (int i = s0 + t; i < e0; i += 256) {
        unsigned p = pk[i];
        int slot = atomicAdd(&hist[p >> 17], 1);
        col_sorted[s0 + slot] = (int)(p & 0x1FFFFu);
    }
}

// ---------------- fused split + bf16x3 MFMA GEMM ----------------
// [y_l | out] = x @ [W_l ; W_r]^T (+bias on out half)
// Block = 64 rows. Stage A hi/lo bf16 in LDS (converted once, XOR-swizzled);
// 4 waves: wave w covers cols 64w..64w+63 (w<2 -> y_l bf16, w>=2 -> out fp32).
__global__ __launch_bounds__(256) void mm_kernel(const float* __restrict__ x,
                                                 const unsigned short* __restrict__ wh,
                                                 const unsigned short* __restrict__ wl,
                                                 const float* __restrict__ bias,
                                                 unsigned short* __restrict__ yl,
                                                 float* __restrict__ out, int n) {
    __shared__ unsigned short AhL[64 * D];   // 16 KB
    __shared__ unsigned short AlL[64 * D];   // 16 KB
    int t = threadIdx.x;
    int w = t >> 6;
    int l = t & 63;
    int ml = l & 15;
    int kq = l >> 4;
    int m0 = blockIdx.x * 64;
    int n0 = w * 64;

    // ---- stage: 64 rows x 128 cols of x, fp32 -> bf16 hi/lo, into swizzled LDS ----
#pragma unroll
    for (int i = 0; i < 8; ++i) {
        int f = t + (i << 8);              // float4 index in tile (2048 total)
        int row = f >> 5;                  // 32 float4 per row
        int c4 = f & 31;
        int rg = m0 + row;
        if (rg > n - 1) rg = n - 1;        // clamp tail
        float4 v = *(const float4*)(x + (size_t)rg * D + (c4 << 2));
        unsigned short h0 = f2bf(v.x), h1 = f2bf(v.y), h2 = f2bf(v.z), h3 = f2bf(v.w);
        float r0 = v.x - __uint_as_float((unsigned)h0 << 16);
        float r1 = v.y - __uint_as_float((unsigned)h1 << 16);
        float r2 = v.z - __uint_as_float((unsigned)h2 << 16);
        float r3 = v.w - __uint_as_float((unsigned)h3 << 16);
        uint2 hh, ll;
        hh.x = (unsigned)h0 | ((unsigned)h1 << 16);
        hh.y = (unsigned)h2 | ((unsigned)h3 << 16);
        ll.x = (unsigned)f2bf(r0) | ((unsigned)f2bf(r1) << 16);
        ll.y = (unsigned)f2bf(r2) | ((unsigned)f2bf(r3) << 16);
        int byte = (row << 8) + (c4 << 3);
        byte ^= (row & 7) << 4;            // XOR swizzle (16B granule)
        *(uint2*)((char*)AhL + byte) = hh;
        *(uint2*)((char*)AlL + byte) = ll;
    }
    __syncthreads();

    f32x4 acc[4][4];
#pragma unroll
    for (int a = 0; a < 4; ++a)
#pragma unroll
        for (int b = 0; b < 4; ++b) acc[a][b] = (f32x4){0.f, 0.f, 0.f, 0.f};

#pragma unroll
    for (int ks = 0; ks < 4; ++ks) {
        short8 Ah[4], Al[4];
#pragma unroll
        for (int mf = 0; mf < 4; ++mf) {
            int row = mf * 16 + ml;
            int byte = (row << 8) + (ks << 6) + (kq << 4);
            byte ^= (row & 7) << 4;
            Ah[mf] = *(const short8*)((const char*)AhL + byte);
            Al[mf] = *(const short8*)((const char*)AlL + byte);
        }
#pragma unroll
        for (int nf = 0; nf < 4; ++nf) {
            size_t boff = (size_t)(n0 + nf * 16 + ml) * D + ks * 32 + kq * 8;
            short8 Bh = *(const short8*)(wh + boff);
            short8 Bl = *(const short8*)(wl + boff);
#pragma unroll
            for (int mf = 0; mf < 4; ++mf) {
                acc[mf][nf] = __builtin_amdgcn_mfma_f32_16x16x32_bf16(Ah[mf], Bh, acc[mf][nf], 0, 0, 0);
                acc[mf][nf] = __builtin_amdgcn_mfma_f32_16x16x32_bf16(Ah[mf], Bl, acc[mf][nf], 0, 0, 0);
                acc[mf][nf] = __builtin_amdgcn_mfma_f32_16x16x32_bf16(Al[mf], Bh, acc[mf][nf], 0, 0, 0);
            }
        }
    }

    if (n0 < D) {
#pragma unroll
        for (int nf = 0; nf < 4; ++nf) {
            int col = n0 + nf * 16 + ml;
#pragma unroll
            for (int mf = 0; mf < 4; ++mf) {
                int rbase = m0 + mf * 16 + kq * 4;
#pragma unroll
                for (int r = 0; r < 4; ++r) {
                    int row = rbase + r;
                    if (row < n) yl[(size_t)row * D + col] = f2bf(acc[mf][nf][r]);
                }
            }
        }
    } else {
#pragma unroll
        for (int nf = 0; nf < 4; ++nf) {
            int col = n0 - D + nf * 16 + ml;
            float bv = bias[col];
#pragma unroll
            for (int mf = 0; mf < 4; ++mf) {
                int rbase = m0 + mf * 16 + kq * 4;
#pragma unroll
                for (int r = 0; r < 4; ++r) {
                    int row = rbase + r;
                    if (row < n) out[(size_t)row * D + col] = acc[mf][nf][r] + bv;
                }
            }
        }
    }
}

// ---------------- gather: one wave per node; out[i] += mean of bf16 y_l rows ----------------
__global__ void gather_kernel(const unsigned short* __restrict__ yl,
                              const int* __restrict__ col_sorted,
                              const int* __restrict__ row_start,
                              float* __restrict__ out, int n) {
    int wave = (int)((blockIdx.x * (size_t)blockDim.x + threadIdx.x) >> 6);
    int lane = threadIdx.x & 63;
    if (wave >= n) return;
    int s = row_start[wave];
    int e = row_start[wave + 1];
    float a0 = 0.f, a1 = 0.f;
    int j = s;
    for (; j + 3 < e; j += 4) {
        int c0 = col_sorted[j], c1 = col_sorted[j + 1], c2 = col_sorted[j + 2], c3 = col_sorted[j + 3];
        unsigned v0 = *(const unsigned*)(yl + (size_t)c0 * D + 2 * lane);
        unsigned v1 = *(const unsigned*)(yl + (size_t)c1 * D + 2 * lane);
        unsigned v2 = *(const unsigned*)(yl + (size_t)c2 * D + 2 * lane);
        unsigned v3 = *(const unsigned*)(yl + (size_t)c3 * D + 2 * lane);
        a0 += __uint_as_float(v0 << 16) + __uint_as_float(v1 << 16) +
              __uint_as_float(v2 << 16) + __uint_as_float(v3 << 16);
        a1 += __uint_as_float(v0 & 0xffff0000u) + __uint_as_float(v1 & 0xffff0000u) +
              __uint_as_float(v2 & 0xffff0000u) + __uint_as_float(v3 & 0xffff0000u);
    }
    for (; j < e; ++j) {
        unsigned v = *(const unsigned*)(yl + (size_t)col_sorted[j] * D + 2 * lane);
        a0 += __uint_as_float(v << 16);
        a1 += __uint_as_float(v & 0xffff0000u);
    }
    float inv = (e > s) ? 1.0f / (float)(e - s) : 0.0f;
    float2* po = (float2*)(out + (size_t)wave * D + 2 * lane);
    float2 cur = *po;
    cur.x += a0 * inv;
    cur.y += a1 * inv;
    *po = cur;
}

extern "C" void kernel_launch(void* const* d_in, const int* in_sizes, int n_in,
                              void* d_out, int out_size, void* d_ws, size_t ws_size,
                              hipStream_t stream) {
    const float* x  = (const float*)d_in[0];
    const int*   ei = (const int*)d_in[1];
    const float* Wl = (const float*)d_in[2];
    const float* bl = (const float*)d_in[3];
    const float* Wr = (const float*)d_in[4];
    const float* br = (const float*)d_in[5];
    float* out = (float*)d_out;

    const int n = in_sizes[0] / D;       // 100000
    const int E = in_sizes[1] / 2;       // 1600000
    const int nbk = (n + NPB - 1) / NPB; // 782 buckets (<= MAXBK)
    const int chunk = (E + NBLK - 1) / NBLK;

    char* p = (char*)d_ws;
    auto alloc = [&](size_t bytes) {
        char* r = p;
        p += (bytes + 1023) & ~(size_t)1023;
        return r;
    };
    int*   row_start  = (int*)alloc((size_t)(n + 1) * 4);
    int*   col_sorted = (int*)alloc((size_t)E * 4);
    int*   cnt        = (int*)alloc((size_t)nbk * NBLK * 4);
    int*   btot       = (int*)alloc((size_t)nbk * 4);
    int*   bbase      = (int*)alloc((size_t)(nbk + 1) * 4);
    unsigned* pk      = (unsigned*)alloc((size_t)E * 4);
    unsigned short* wh   = (unsigned short*)alloc((size_t)2 * D * D * 2);
    unsigned short* wlsp = (unsigned short*)alloc((size_t)2 * D * D * 2);
    float* bias       = (float*)alloc((size_t)D * 4);
    unsigned short* yl = (unsigned short*)alloc((size_t)n * D * 2);

    prepw_kernel<<<(2 * D * D + 255) / 256, 256, 0, stream>>>(Wl, bl, Wr, br, wh, wlsp, bias);
    hist_kernel<<<NBLK, 256, 0, stream>>>(ei, cnt, E, nbk, chunk);
    scan_cnt_kernel<<<nbk, 256, 0, stream>>>(cnt, btot);
    scan_btot_kernel<<<1, 1024, 0, stream>>>(btot, bbase, row_start, nbk, n);
    scatter_kernel<<<NBLK, 256, 0, stream>>>(ei, cnt, bbase, pk, E, nbk, chunk);
    place_kernel<<<nbk, 256, 0, stream>>>(bbase, pk, row_start, col_sorted, n);
    mm_kernel<<<(n + 63) / 64, 256, 0, stream>>>(x, wh, wlsp, bias, yl, out, n);
    gather_kernel<<<(n * 64 + 255) / 256, 256, 0, stream>>>(yl, col_sorted, row_start, out, n);
}

// Round 10
// 269.647 us; speedup vs baseline: 2.7563x; 1.0335x over previous
//
#include <hip/hip_runtime.h>

#define D 128
#define NPB 128          // nodes per bucket (row >> 7)
#define MAXBK 800        // max buckets (n <= 102400)
#define NBLK 256         // partition grid (hist/scatter), also cnt stride

typedef __attribute__((ext_vector_type(8))) short short8;
typedef __attribute__((ext_vector_type(4))) float f32x4;

__device__ __forceinline__ unsigned short f2bf(float f) {
    unsigned u = __float_as_uint(f);
    return (unsigned short)((u + 0x7fffu + ((u >> 16) & 1u)) >> 16);
}

// ---------------- pass 1: per-block LDS histogram by bucket (+ folded weight prep) ----------------
// blocks [0,NBLK): histogram; blocks [NBLK, NBLK+128): weight hi/lo split + bias
__global__ __launch_bounds__(256) void hist_kernel(const int* __restrict__ ei,
                                                   int* __restrict__ cnt,
                                                   const float* __restrict__ Wl_in, const float* __restrict__ bl,
                                                   const float* __restrict__ Wr_in, const float* __restrict__ br,
                                                   unsigned short* __restrict__ wh, unsigned short* __restrict__ wl,
                                                   float* __restrict__ bias,
                                                   int E, int nbk, int chunk) {
    __shared__ int h[MAXBK];
    int b = blockIdx.x, t = threadIdx.x;
    if (b >= NBLK) {
        // ---- folded prepw ----
        int t2 = (b - NBLK) * 256 + t;
        if (t2 < 2 * D * D) {
            int nn = t2 >> 7;
            int k = t2 & (D - 1);
            float v = (nn < D) ? Wl_in[nn * D + k] : Wr_in[(nn - D) * D + k];
            unsigned short hh = f2bf(v);
            float r = v - __uint_as_float((unsigned)hh << 16);
            wh[t2] = hh;
            wl[t2] = f2bf(r);
        }
        if (t2 < D) bias[t2] = bl[t2] + br[t2];
        return;
    }
    for (int i = t; i < nbk; i += 256) h[i] = 0;
    __syncthreads();
    int lo = b * chunk, hi = min(E, lo + chunk);
    for (int e = lo + t; e < hi; e += 256)
        atomicAdd(&h[ei[e] >> 7], 1);
    __syncthreads();
    for (int i = t; i < nbk; i += 256) cnt[i * NBLK + b] = h[i];
}

// ---------------- pass 2a: exclusive scan of each bucket's 256 block-counts ----------------
__global__ __launch_bounds__(256) void scan_cnt_kernel(int* __restrict__ cnt,
                                                       int* __restrict__ btot) {
    int b = blockIdx.x, t = threadIdx.x;
    int lane = t & 63, w = t >> 6;
    int v = cnt[b * NBLK + t];
    int s = v;
    for (int off = 1; off < 64; off <<= 1) {
        int u = __shfl_up(s, off, 64);
        if (lane >= off) s += u;
    }
    __shared__ int wsum[4], woff[4];
    if (lane == 63) wsum[w] = s;
    __syncthreads();
    if (t == 0) {
        int run = 0;
        for (int i = 0; i < 4; ++i) { woff[i] = run; run += wsum[i]; }
        btot[b] = run;
    }
    __syncthreads();
    cnt[b * NBLK + t] = s - v + woff[w];   // exclusive prefix within bucket
}

// ---------------- pass 2b: exclusive scan of bucket totals ----------------
__global__ void scan_btot_kernel(const int* __restrict__ btot, int* __restrict__ bbase,
                                 int* __restrict__ row_start, int nbk, int n) {
    __shared__ int s[1024];
    int t = threadIdx.x;
    int v = (t < nbk) ? btot[t] : 0;
    s[t] = v;
    __syncthreads();
    for (int off = 1; off < 1024; off <<= 1) {
        int u = (t >= off) ? s[t - off] : 0;
        __syncthreads();
        s[t] += u;
        __syncthreads();
    }
    if (t < nbk) bbase[t] = s[t] - v;
    if (t == 1023) { bbase[nbk] = s[1023]; row_start[n] = s[1023]; }
}

// ---------------- pass 3: scatter packed (row&127)<<17|col into per-(block,bucket) regions ----------------
__global__ __launch_bounds__(256) void scatter_kernel(const int* __restrict__ ei,
                                                      const int* __restrict__ cnt,
                                                      const int* __restrict__ bbase,
                                                      unsigned* __restrict__ pk,
                                                      int E, int nbk, int chunk) {
    __shared__ int curs[MAXBK];
    int b = blockIdx.x, t = threadIdx.x;
    for (int i = t; i < nbk; i += 256) curs[i] = bbase[i] + cnt[i * NBLK + b];
    __syncthreads();
    int lo = b * chunk, hi = min(E, lo + chunk);
    for (int e = lo + t; e < hi; e += 256) {
        int r = ei[e];
        int c = ei[E + e];
        int pos = atomicAdd(&curs[r >> 7], 1);
        pk[pos] = ((unsigned)(r & (NPB - 1)) << 17) | (unsigned)c;
    }
}

// ---------------- per-bucket: histogram rows -> row_start; place cols ----------------
__global__ __launch_bounds__(256) void place_kernel(const int* __restrict__ bbase,
                                                    const unsigned* __restrict__ pk,
                                                    int* __restrict__ row_start,
                                                    int* __restrict__ col_sorted, int n) {
    __shared__ int hist[NPB];
    __shared__ int pre[NPB];
    int b = blockIdx.x, t = threadIdx.x;
    if (t < NPB) hist[t] = 0;
    __syncthreads();
    int s0 = bbase[b], e0 = bbase[b + 1];
    for (int i = s0 + t; i < e0; i += 256)
        atomicAdd(&hist[pk[i] >> 17], 1);
    __syncthreads();
    if (t < NPB) pre[t] = hist[t];
    __syncthreads();
    for (int off = 1; off < NPB; off <<= 1) {
        int u = (t >= off && t < NPB) ? pre[t - off] : 0;
        __syncthreads();
        if (t < NPB) pre[t] += u;
        __syncthreads();
    }
    if (t < NPB) {
        int ex = pre[t] - hist[t];
        int node = b * NPB + t;
        if (node < n) row_start[node] = s0 + ex;
        hist[t] = ex;                   // reuse as cursor
    }
    __syncthreads();
    for (int i = s0 + t; i < e0; i += 256) {
        unsigned p = pk[i];
        int slot = atomicAdd(&hist[p >> 17], 1);
        col_sorted[s0 + slot] = (int)(p & 0x1FFFFu);
    }
}

// ---------------- fused split + bf16x3 MFMA GEMM ----------------
__global__ __launch_bounds__(256) void mm_kernel(const float* __restrict__ x,
                                                 const unsigned short* __restrict__ wh,
                                                 const unsigned short* __restrict__ wl,
                                                 const float* __restrict__ bias,
                                                 unsigned short* __restrict__ yl,
                                                 float* __restrict__ out, int n) {
    __shared__ unsigned short AhL[64 * D];   // 16 KB
    __shared__ unsigned short AlL[64 * D];   // 16 KB
    int t = threadIdx.x;
    int w = t >> 6;
    int l = t & 63;
    int ml = l & 15;
    int kq = l >> 4;
    int m0 = blockIdx.x * 64;
    int n0 = w * 64;

    // ---- stage: 64 rows x 128 cols of x, fp32 -> bf16 hi/lo, into swizzled LDS ----
#pragma unroll
    for (int i = 0; i < 8; ++i) {
        int f = t + (i << 8);              // float4 index in tile (2048 total)
        int row = f >> 5;                  // 32 float4 per row
        int c4 = f & 31;
        int rg = m0 + row;
        if (rg > n - 1) rg = n - 1;        // clamp tail
        float4 v = *(const float4*)(x + (size_t)rg * D + (c4 << 2));
        unsigned short h0 = f2bf(v.x), h1 = f2bf(v.y), h2 = f2bf(v.z), h3 = f2bf(v.w);
        float r0 = v.x - __uint_as_float((unsigned)h0 << 16);
        float r1 = v.y - __uint_as_float((unsigned)h1 << 16);
        float r2 = v.z - __uint_as_float((unsigned)h2 << 16);
        float r3 = v.w - __uint_as_float((unsigned)h3 << 16);
        uint2 hh, ll;
        hh.x = (unsigned)h0 | ((unsigned)h1 << 16);
        hh.y = (unsigned)h2 | ((unsigned)h3 << 16);
        ll.x = (unsigned)f2bf(r0) | ((unsigned)f2bf(r1) << 16);
        ll.y = (unsigned)f2bf(r2) | ((unsigned)f2bf(r3) << 16);
        int byte = (row << 8) + (c4 << 3);
        byte ^= (row & 7) << 4;            // XOR swizzle (16B granule)
        *(uint2*)((char*)AhL + byte) = hh;
        *(uint2*)((char*)AlL + byte) = ll;
    }
    __syncthreads();

    f32x4 acc[4][4];
#pragma unroll
    for (int a = 0; a < 4; ++a)
#pragma unroll
        for (int b = 0; b < 4; ++b) acc[a][b] = (f32x4){0.f, 0.f, 0.f, 0.f};

#pragma unroll
    for (int ks = 0; ks < 4; ++ks) {
        short8 Ah[4], Al[4];
#pragma unroll
        for (int mf = 0; mf < 4; ++mf) {
            int row = mf * 16 + ml;
            int byte = (row << 8) + (ks << 6) + (kq << 4);
            byte ^= (row & 7) << 4;
            Ah[mf] = *(const short8*)((const char*)AhL + byte);
            Al[mf] = *(const short8*)((const char*)AlL + byte);
        }
#pragma unroll
        for (int nf = 0; nf < 4; ++nf) {
            size_t boff = (size_t)(n0 + nf * 16 + ml) * D + ks * 32 + kq * 8;
            short8 Bh = *(const short8*)(wh + boff);
            short8 Bl = *(const short8*)(wl + boff);
#pragma unroll
            for (int mf = 0; mf < 4; ++mf) {
                acc[mf][nf] = __builtin_amdgcn_mfma_f32_16x16x32_bf16(Ah[mf], Bh, acc[mf][nf], 0, 0, 0);
                acc[mf][nf] = __builtin_amdgcn_mfma_f32_16x16x32_bf16(Ah[mf], Bl, acc[mf][nf], 0, 0, 0);
                acc[mf][nf] = __builtin_amdgcn_mfma_f32_16x16x32_bf16(Al[mf], Bh, acc[mf][nf], 0, 0, 0);
            }
        }
    }

    if (n0 < D) {
#pragma unroll
        for (int nf = 0; nf < 4; ++nf) {
            int col = n0 + nf * 16 + ml;
#pragma unroll
            for (int mf = 0; mf < 4; ++mf) {
                int rbase = m0 + mf * 16 + kq * 4;
#pragma unroll
                for (int r = 0; r < 4; ++r) {
                    int row = rbase + r;
                    if (row < n) yl[(size_t)row * D + col] = f2bf(acc[mf][nf][r]);
                }
            }
        }
    } else {
#pragma unroll
        for (int nf = 0; nf < 4; ++nf) {
            int col = n0 - D + nf * 16 + ml;
            float bv = bias[col];
#pragma unroll
            for (int mf = 0; mf < 4; ++mf) {
                int rbase = m0 + mf * 16 + kq * 4;
#pragma unroll
                for (int r = 0; r < 4; ++r) {
                    int row = rbase + r;
                    if (row < n) out[(size_t)row * D + col] = acc[mf][nf][r] + bv;
                }
            }
        }
    }
}

// ---------------- gather: one wave per node, 2 edges/wave (32-lane halves, uint2 loads) ----------------
__global__ void gather_kernel(const unsigned short* __restrict__ yl,
                              const int* __restrict__ col_sorted,
                              const int* __restrict__ row_start,
                              float* __restrict__ out, int n) {
    int wave = (int)((blockIdx.x * (size_t)blockDim.x + threadIdx.x) >> 6);
    int lane = threadIdx.x & 63;
    int half = lane >> 5;        // which edge of the pair
    int sub = lane & 31;         // 4-element slot within the row
    if (wave >= n) return;
    int s = row_start[wave];
    int e = row_start[wave + 1];
    float a0 = 0.f, a1 = 0.f, a2 = 0.f, a3 = 0.f;
    int j = s;
    // 4-pair unroll: 8 rows in flight per wave
    for (; j + 7 < e; j += 8) {
        int c0 = col_sorted[j + half];
        int c1 = col_sorted[j + 2 + half];
        int c2 = col_sorted[j + 4 + half];
        int c3 = col_sorted[j + 6 + half];
        uint2 v0 = *(const uint2*)(yl + (size_t)c0 * D + sub * 4);
        uint2 v1 = *(const uint2*)(yl + (size_t)c1 * D + sub * 4);
        uint2 v2 = *(const uint2*)(yl + (size_t)c2 * D + sub * 4);
        uint2 v3 = *(const uint2*)(yl + (size_t)c3 * D + sub * 4);
        a0 += __uint_as_float(v0.x << 16) + __uint_as_float(v1.x << 16) +
              __uint_as_float(v2.x << 16) + __uint_as_float(v3.x << 16);
        a1 += __uint_as_float(v0.x & 0xffff0000u) + __uint_as_float(v1.x & 0xffff0000u) +
              __uint_as_float(v2.x & 0xffff0000u) + __uint_as_float(v3.x & 0xffff0000u);
        a2 += __uint_as_float(v0.y << 16) + __uint_as_float(v1.y << 16) +
              __uint_as_float(v2.y << 16) + __uint_as_float(v3.y << 16);
        a3 += __uint_as_float(v0.y & 0xffff0000u) + __uint_as_float(v1.y & 0xffff0000u) +
              __uint_as_float(v2.y & 0xffff0000u) + __uint_as_float(v3.y & 0xffff0000u);
    }
    for (; j + 1 < e; j += 2) {
        int c = col_sorted[j + half];
        uint2 v = *(const uint2*)(yl + (size_t)c * D + sub * 4);
        a0 += __uint_as_float(v.x << 16);
        a1 += __uint_as_float(v.x & 0xffff0000u);
        a2 += __uint_as_float(v.y << 16);
        a3 += __uint_as_float(v.y & 0xffff0000u);
    }
    if (j < e && half == 0) {    // single leftover edge: half-0 lanes cover the row
        int c = col_sorted[j];
        uint2 v = *(const uint2*)(yl + (size_t)c * D + sub * 4);
        a0 += __uint_as_float(v.x << 16);
        a1 += __uint_as_float(v.x & 0xffff0000u);
        a2 += __uint_as_float(v.y << 16);
        a3 += __uint_as_float(v.y & 0xffff0000u);
    }
    // cross-half reduce: both halves accumulate disjoint edge sets for the SAME 4 elems
    a0 += __shfl_xor(a0, 32, 64);
    a1 += __shfl_xor(a1, 32, 64);
    a2 += __shfl_xor(a2, 32, 64);
    a3 += __shfl_xor(a3, 32, 64);
    float inv = (e > s) ? 1.0f / (float)(e - s) : 0.0f;
    float2* po = (float2*)(out + (size_t)wave * D + sub * 4 + half * 2);
    float2 cur = *po;
    cur.x += (half ? a2 : a0) * inv;
    cur.y += (half ? a3 : a1) * inv;
    *po = cur;
}

extern "C" void kernel_launch(void* const* d_in, const int* in_sizes, int n_in,
                              void* d_out, int out_size, void* d_ws, size_t ws_size,
                              hipStream_t stream) {
    const float* x  = (const float*)d_in[0];
    const int*   ei = (const int*)d_in[1];
    const float* Wl = (const float*)d_in[2];
    const float* bl = (const float*)d_in[3];
    const float* Wr = (const float*)d_in[4];
    const float* br = (const float*)d_in[5];
    float* out = (float*)d_out;

    const int n = in_sizes[0] / D;       // 100000
    const int E = in_sizes[1] / 2;       // 1600000
    const int nbk = (n + NPB - 1) / NPB; // 782 buckets (<= MAXBK)
    const int chunk = (E + NBLK - 1) / NBLK;

    char* p = (char*)d_ws;
    auto alloc = [&](size_t bytes) {
        char* r = p;
        p += (bytes + 1023) & ~(size_t)1023;
        return r;
    };
    int*   row_start  = (int*)alloc((size_t)(n + 1) * 4);
    int*   col_sorted = (int*)alloc((size_t)E * 4);
    int*   cnt        = (int*)alloc((size_t)nbk * NBLK * 4);
    int*   btot       = (int*)alloc((size_t)nbk * 4);
    int*   bbase      = (int*)alloc((size_t)(nbk + 1) * 4);
    unsigned* pk      = (unsigned*)alloc((size_t)E * 4);
    unsigned short* wh   = (unsigned short*)alloc((size_t)2 * D * D * 2);
    unsigned short* wlsp = (unsigned short*)alloc((size_t)2 * D * D * 2);
    float* bias       = (float*)alloc((size_t)D * 4);
    unsigned short* yl = (unsigned short*)alloc((size_t)n * D * 2);

    hist_kernel<<<NBLK + 128, 256, 0, stream>>>(ei, cnt, Wl, bl, Wr, br, wh, wlsp, bias, E, nbk, chunk);
    scan_cnt_kernel<<<nbk, 256, 0, stream>>>(cnt, btot);
    scan_btot_kernel<<<1, 1024, 0, stream>>>(btot, bbase, row_start, nbk, n);
    scatter_kernel<<<NBLK, 256, 0, stream>>>(ei, cnt, bbase, pk, E, nbk, chunk);
    place_kernel<<<nbk, 256, 0, stream>>>(bbase, pk, row_start, col_sorted, n);
    mm_kernel<<<(n + 63) / 64, 256, 0, stream>>>(x, wh, wlsp, bias, yl, out, n);
    gather_kernel<<<(n * 64 + 255) / 256, 256, 0, stream>>>(yl, col_sorted, row_start, out, n);
}